// Round 1
// baseline (1010.429 us; speedup 1.0000x reference)
//
#include <hip/hip_runtime.h>
#include <math.h>

// ---------------- static problem config ----------------
#define N_NODES   100000
#define N_GRAPHS  100
#define NPG       1000
#define N_EDGES   1600000
#define EPG       16000      // edges per graph
#define IN_DIM    64
#define POS_DIM   16
#define HID       16
#define HEADS     4
#define HD        64         // HEADS*HID
#define OUT_DIM   10
#define BN_EPS    1e-5f
#define NEG_SLOPE 0.2f

// ---------------- workspace layout (float elements) ----------------
// h0      : [N,80]          8,000,000
// hlin_p  : [N,64]          6,400,000
// hlin_d  : [N,64]          6,400,000
// gat_cat : [N,128]        12,800,000
// F0 (h1) : [N,64]          6,400,000
// F1 (h2) : [N,64]          6,400,000
// s_p,d_p,s_d,d_d : [N,4] each  400,000 x4
// stats   : 128
// csr_off : int[100001]
// sorted_src : int[1,600,000]
static const size_t OFF_H0    = 0;
static const size_t OFF_HLP   = 8000000;
static const size_t OFF_HLD   = 14400000;
static const size_t OFF_CAT   = 20800000;
static const size_t OFF_F0    = 33600000;
static const size_t OFF_F1    = 40000000;
static const size_t OFF_SP    = 46400000;
static const size_t OFF_DP    = 46800000;
static const size_t OFF_SD    = 47200000;
static const size_t OFF_DD    = 47600000;
static const size_t OFF_STATS = 48000000;  // 128 floats (sum[64], sumsq[64])
static const size_t OFF_CSR   = 48000128;  // int region starts here (float-offset*4 bytes)
static const size_t OFF_SRT   = 48100144;  // ints

// ---------------- h0 = [x | pos @ pe_W + pe_b] ----------------
__global__ void build_h0(const float* __restrict__ x, const float* __restrict__ peW,
                         const float* __restrict__ peb, float* __restrict__ h0) {
    int idx = blockIdx.x * blockDim.x + threadIdx.x;
    if (idx >= N_NODES * 80) return;
    int n = idx / 80;
    int c = idx - n * 80;
    if (c < 64) {
        h0[idx] = x[n * 64 + c];
    } else {
        int r = n % NPG;
        float px = (float)(r >> 5) * (1.0f / 31.0f);
        float py = (float)(r & 31) * (1.0f / 31.0f);
        int cc = c - 64;
        h0[idx] = px * peW[cc] + py * peW[16 + cc] + peb[cc];
    }
}

// ---------------- per-graph counting sort of edges by dst ----------------
__global__ __launch_bounds__(1024) void sort_edges(const int* __restrict__ ei,
                                                   int* __restrict__ csr_off,
                                                   int* __restrict__ sorted_src) {
    __shared__ int hist[1024];
    __shared__ int scan[1024];
    const int g = blockIdx.x;
    const int t = threadIdx.x;
    const int* src = ei;
    const int* dst = ei + N_EDGES;
    const int e0 = g * EPG;
    const int nbase = g * NPG;

    hist[t] = 0;
    __syncthreads();
    for (int i = t; i < EPG; i += 1024) {
        int d = dst[e0 + i] - nbase;
        atomicAdd(&hist[d], 1);
    }
    __syncthreads();
    // inclusive Hillis-Steele scan over 1024
    scan[t] = hist[t];
    __syncthreads();
    for (int off = 1; off < 1024; off <<= 1) {
        int v = (t >= off) ? scan[t - off] : 0;
        __syncthreads();
        scan[t] += v;
        __syncthreads();
    }
    int excl = scan[t] - hist[t];
    if (t < NPG) csr_off[nbase + t] = e0 + excl;
    if (g == 0 && t == 0) csr_off[N_NODES] = N_EDGES;
    __syncthreads();
    hist[t] = excl;   // running counters
    __syncthreads();
    for (int i = t; i < EPG; i += 1024) {
        int s = src[e0 + i];
        int d = dst[e0 + i] - nbase;
        int slot = atomicAdd(&hist[d], 1);
        sorted_src[e0 + slot] = s;
    }
}

// ---------------- dual GEMM: hlin_p = A@Wp, hlin_d = A@Wd  (N x DIN @ DIN x 64) ----------------
template <int DIN>
__global__ __launch_bounds__(256) void gemm_dual(const float* __restrict__ A,
                                                 const float* __restrict__ Wp,
                                                 const float* __restrict__ Wd,
                                                 float* __restrict__ outp,
                                                 float* __restrict__ outd) {
    __shared__ float sWp[DIN * 64];
    __shared__ float sWd[DIN * 64];
    __shared__ float sH[64 * DIN];
    const int t = threadIdx.x;
    for (int i = t; i < DIN * 64; i += 256) { sWp[i] = Wp[i]; sWd[i] = Wd[i]; }
    const int node0 = blockIdx.x * 64;
    const int limit = (N_NODES - node0) * DIN;
    for (int i = t; i < 64 * DIN; i += 256) sH[i] = (i < limit) ? A[node0 * DIN + i] : 0.0f;
    __syncthreads();

    const int c = t & 63, q = t >> 6;
    float accp[16], accd[16];
#pragma unroll
    for (int j = 0; j < 16; ++j) { accp[j] = 0.f; accd[j] = 0.f; }

    for (int k = 0; k < DIN; k += 4) {
        float wp0 = sWp[(k + 0) * 64 + c], wp1 = sWp[(k + 1) * 64 + c];
        float wp2 = sWp[(k + 2) * 64 + c], wp3 = sWp[(k + 3) * 64 + c];
        float wd0 = sWd[(k + 0) * 64 + c], wd1 = sWd[(k + 1) * 64 + c];
        float wd2 = sWd[(k + 2) * 64 + c], wd3 = sWd[(k + 3) * 64 + c];
#pragma unroll
        for (int j = 0; j < 16; ++j) {
            const float4 h4 = *reinterpret_cast<const float4*>(&sH[(q * 16 + j) * DIN + k]);
            accp[j] = fmaf(h4.w, wp3, fmaf(h4.z, wp2, fmaf(h4.y, wp1, fmaf(h4.x, wp0, accp[j]))));
            accd[j] = fmaf(h4.w, wd3, fmaf(h4.z, wd2, fmaf(h4.y, wd1, fmaf(h4.x, wd0, accd[j]))));
        }
    }
#pragma unroll
    for (int j = 0; j < 16; ++j) {
        int node = node0 + q * 16 + j;
        if (node < N_NODES) {
            outp[node * 64 + c] = accp[j];
            outd[node * 64 + c] = accd[j];
        }
    }
}

// ---------------- single GEMM (+bias, optional BN-stat accumulation) ----------------
template <int K, bool STATS>
__global__ __launch_bounds__(256) void gemm_single(const float* __restrict__ A,
                                                   const float* __restrict__ W,
                                                   const float* __restrict__ bias,
                                                   float* __restrict__ out,
                                                   float* __restrict__ stats) {
    __shared__ float sW[K * 64];
    __shared__ float sH[64 * K];
    const int t = threadIdx.x;
    for (int i = t; i < K * 64; i += 256) sW[i] = W[i];
    const int node0 = blockIdx.x * 64;
    const int limit = (N_NODES - node0) * K;
    for (int i = t; i < 64 * K; i += 256) sH[i] = (i < limit) ? A[node0 * K + i] : 0.0f;
    __syncthreads();

    const int c = t & 63, q = t >> 6;
    float acc[16];
#pragma unroll
    for (int j = 0; j < 16; ++j) acc[j] = 0.f;

    for (int k = 0; k < K; k += 4) {
        float w0 = sW[(k + 0) * 64 + c], w1 = sW[(k + 1) * 64 + c];
        float w2 = sW[(k + 2) * 64 + c], w3 = sW[(k + 3) * 64 + c];
#pragma unroll
        for (int j = 0; j < 16; ++j) {
            const float4 h4 = *reinterpret_cast<const float4*>(&sH[(q * 16 + j) * K + k]);
            acc[j] = fmaf(h4.w, w3, fmaf(h4.z, w2, fmaf(h4.y, w1, fmaf(h4.x, w0, acc[j]))));
        }
    }
    const float bc = bias[c];
    float lsum = 0.f, lsq = 0.f;
#pragma unroll
    for (int j = 0; j < 16; ++j) {
        int node = node0 + q * 16 + j;
        if (node < N_NODES) {
            float v = acc[j] + bc;
            out[node * 64 + c] = v;
            lsum += v;
            lsq += v * v;
        }
    }
    if (STATS) {
        __syncthreads();                 // sH no longer needed; reuse for reduction
        float* red = sH;                 // 512 floats used
        red[t] = lsum;
        red[256 + t] = lsq;
        __syncthreads();
        if (t < 64) {
            float s  = red[c] + red[64 + c] + red[128 + c] + red[192 + c];
            float sq = red[256 + c] + red[320 + c] + red[384 + c] + red[448 + c];
            atomicAdd(&stats[c], s);
            atomicAdd(&stats[64 + c], sq);
        }
    }
}

// ---------------- per-(node,head) attention logits ----------------
__global__ void compute_sd(const float* __restrict__ hp, const float* __restrict__ hd,
                           const float* __restrict__ pas, const float* __restrict__ pad_,
                           const float* __restrict__ das, const float* __restrict__ dad,
                           float* __restrict__ sp, float* __restrict__ dp,
                           float* __restrict__ sd, float* __restrict__ dd) {
    int idx = blockIdx.x * blockDim.x + threadIdx.x;
    if (idx >= N_NODES * 4) return;
    int n = idx >> 2, h = idx & 3;
    const float* rowp = hp + n * 64 + h * 16;
    const float* rowd = hd + n * 64 + h * 16;
    float ap = 0.f, bp = 0.f, ad = 0.f, bd = 0.f;
#pragma unroll
    for (int i = 0; i < 16; ++i) {
        float vp = rowp[i], vd = rowd[i];
        ap += vp * pas[h * 16 + i];
        bp += vp * pad_[h * 16 + i];
        ad += vd * das[h * 16 + i];
        bd += vd * dad[h * 16 + i];
    }
    sp[idx] = ap; dp[idx] = bp; sd[idx] = ad; dd[idx] = bd;
}

// ---------------- fused dual-GAT aggregation: one wave per dst node ----------------
__global__ __launch_bounds__(256) void gat_agg(const float* __restrict__ hlin_p,
                                               const float* __restrict__ hlin_d,
                                               const float* __restrict__ s_p,
                                               const float* __restrict__ d_p,
                                               const float* __restrict__ s_d,
                                               const float* __restrict__ d_d,
                                               const int* __restrict__ csr_off,
                                               const int* __restrict__ sorted_src,
                                               const float* __restrict__ posW,
                                               const float* __restrict__ posb,
                                               float* __restrict__ gat_cat) {
    int v = blockIdx.x * 4 + (threadIdx.x >> 6);
    if (v >= N_NODES) return;
    const int lane = threadIdx.x & 63;
    const int head = lane >> 4;

    const float dpv = d_p[v * 4 + head];
    const float ddv = d_d[v * 4 + head];
    int r = v % NPG;
    const float px = (float)(r >> 5) * (1.0f / 31.0f);
    const float py = (float)(r & 31) * (1.0f / 31.0f);
    const float pw0 = posW[head], pw1 = posW[4 + head], pb = posb[head];

    const int beg = csr_off[v];
    const int end = csr_off[v + 1];
    float accp = 0.f, accd = 0.f, denp = 0.f, dend = 0.f;
    for (int e = beg; e < end; ++e) {
        int src = sorted_src[e];
        int rs = src % NPG;
        float sx = (float)(rs >> 5) * (1.0f / 31.0f);
        float sy = (float)(rs & 31) * (1.0f / 31.0f);
        float extra = (px - sx) * pw0 + (py - sy) * pw1 + pb;
        float ep = s_p[src * 4 + head] + dpv + extra;
        float ed = s_d[src * 4 + head] + ddv;
        ep = fmaxf(ep, NEG_SLOPE * ep);     // leaky_relu (slope<1)
        ed = fmaxf(ed, NEG_SLOPE * ed);
        float pp = __expf(ep);
        float pd = __expf(ed);
        accp += pp * hlin_p[src * 64 + lane];
        accd += pd * hlin_d[src * 64 + lane];
        denp += pp;
        dend += pd;
    }
    gat_cat[v * 128 + lane]      = accp / (denp + 1e-16f);
    gat_cat[v * 128 + 64 + lane] = accd / (dend + 1e-16f);
}

// ---------------- BN (from accumulated stats) + ELU (+ optional residual add) ----------------
__global__ void bn_elu(float* __restrict__ F, const float* __restrict__ stats,
                       const float* __restrict__ gamma, const float* __restrict__ beta,
                       const float* __restrict__ res) {
    int idx = blockIdx.x * blockDim.x + threadIdx.x;
    if (idx >= N_NODES * 64) return;
    int c = idx & 63;
    float mu = stats[c] * (1.0f / (float)N_NODES);
    float var = stats[64 + c] * (1.0f / (float)N_NODES) - mu * mu;
    float inv = rsqrtf(var + BN_EPS);
    float v = (F[idx] - mu) * inv * gamma[c] + beta[c];
    v = (v > 0.f) ? v : expm1f(v);
    if (res) v += res[idx];
    F[idx] = v;
}

// ---------------- mean pool per graph + task head ----------------
__global__ __launch_bounds__(256) void pool_task(const float* __restrict__ h2,
                                                 const float* __restrict__ taskW,
                                                 const float* __restrict__ taskb,
                                                 float* __restrict__ out) {
    __shared__ float red[256];
    __shared__ float pooled[64];
    const int g = blockIdx.x;
    const int t = threadIdx.x;
    const int c = t & 63, q = t >> 6;
    float acc = 0.f;
    for (int nl = q; nl < NPG; nl += 4) acc += h2[(g * NPG + nl) * 64 + c];
    red[t] = acc;
    __syncthreads();
    if (t < 64) pooled[c] = (red[c] + red[64 + c] + red[128 + c] + red[192 + c]) * (1.0f / (float)NPG);
    __syncthreads();
    if (t < OUT_DIM) {
        float o = taskb[t];
        for (int cc = 0; cc < 64; ++cc) o += pooled[cc] * taskW[cc * OUT_DIM + t];
        out[g * OUT_DIM + t] = o;
    }
}

// ---------------- head-diversity loss for both layers ----------------
__global__ __launch_bounds__(256) void div_loss(const float* __restrict__ dW0,
                                                const float* __restrict__ dW1,
                                                float* __restrict__ out) {
    __shared__ float red[16][16];
    float total = 0.f;
    for (int layer = 0; layer < 2; ++layer) {
        const float* W = layer ? dW1 : dW0;
        const int din = layer ? 64 : 80;
        const int p = threadIdx.x & 15;       // pair index: i = p>>2, j = p&3
        const int s16 = threadIdx.x >> 4;     // 0..15 strided workers
        const int i = p >> 2, j = p & 3;
        float acc = 0.f;
        const int Kk = din * 16;
        for (int kk = s16; kk < Kk; kk += 16) {
            int rrow = kk >> 4, cc = kk & 15;
            acc += W[rrow * 64 + i * 16 + cc] * W[rrow * 64 + j * 16 + cc];
        }
        red[p][s16] = acc;
        __syncthreads();
        if (threadIdx.x < 16) {
            float s = 0.f;
            for (int m = 0; m < 16; ++m) s += red[threadIdx.x][m];
            red[threadIdx.x][0] = s;
        }
        __syncthreads();
        if (threadIdx.x == 0) {
            float G[4][4], nrm[4];
            for (int a = 0; a < 4; ++a)
                for (int b = 0; b < 4; ++b) G[a][b] = red[a * 4 + b][0];
            for (int a = 0; a < 4; ++a) nrm[a] = sqrtf(G[a][a]) + 1e-12f;
            float l = 0.f;
            for (int a = 0; a < 4; ++a)
                for (int b = 0; b < 4; ++b) {
                    float gn = G[a][b] / (nrm[a] * nrm[b]);
                    float off = gn - (a == b ? 1.f : 0.f);
                    l += off * off;
                }
            total += 0.1f * l / 12.f;
        }
        __syncthreads();
    }
    if (threadIdx.x == 0) *out = total;
}

// ---------------- launcher ----------------
extern "C" void kernel_launch(void* const* d_in, const int* in_sizes, int n_in,
                              void* d_out, int out_size, void* d_ws, size_t ws_size,
                              hipStream_t stream) {
    const float* x      = (const float*)d_in[0];
    const int*   ei     = (const int*)d_in[1];
    // d_in[2] = batch (derivable: node/1000)
    const float* peW    = (const float*)d_in[3];
    const float* peb    = (const float*)d_in[4];

    const float* l_pW[2]   = {(const float*)d_in[5],  (const float*)d_in[17]};
    const float* l_pas[2]  = {(const float*)d_in[6],  (const float*)d_in[18]};
    const float* l_pad[2]  = {(const float*)d_in[7],  (const float*)d_in[19]};
    const float* l_posW[2] = {(const float*)d_in[8],  (const float*)d_in[20]};
    const float* l_posb[2] = {(const float*)d_in[9],  (const float*)d_in[21]};
    const float* l_dW[2]   = {(const float*)d_in[10], (const float*)d_in[22]};
    const float* l_das[2]  = {(const float*)d_in[11], (const float*)d_in[23]};
    const float* l_dad[2]  = {(const float*)d_in[12], (const float*)d_in[24]};
    const float* l_fW[2]   = {(const float*)d_in[13], (const float*)d_in[25]};
    const float* l_fb[2]   = {(const float*)d_in[14], (const float*)d_in[26]};
    const float* l_g[2]    = {(const float*)d_in[15], (const float*)d_in[27]};
    const float* l_b[2]    = {(const float*)d_in[16], (const float*)d_in[28]};
    const float* res_W  = (const float*)d_in[29];
    const float* res_b  = (const float*)d_in[30];
    const float* task_W = (const float*)d_in[31];
    const float* task_b = (const float*)d_in[32];

    float* ws = (float*)d_ws;
    float* h0      = ws + OFF_H0;
    float* hlin_p  = ws + OFF_HLP;
    float* hlin_d  = ws + OFF_HLD;
    float* gat_cat = ws + OFF_CAT;
    float* F0      = ws + OFF_F0;
    float* F1      = ws + OFF_F1;
    float* s_p     = ws + OFF_SP;
    float* d_p     = ws + OFF_DP;
    float* s_d     = ws + OFF_SD;
    float* d_d     = ws + OFF_DD;
    float* stats   = ws + OFF_STATS;
    int*   csr_off    = (int*)(ws + OFF_CSR);
    int*   sorted_src = (int*)(ws + OFF_SRT);
    float* out = (float*)d_out;

    const int GB = 256;

    build_h0<<<(N_NODES * 80 + GB - 1) / GB, GB, 0, stream>>>(x, peW, peb, h0);
    sort_edges<<<N_GRAPHS, 1024, 0, stream>>>(ei, csr_off, sorted_src);

    const int GEMM_BLOCKS = (N_NODES + 63) / 64;   // 1563

    // ----- layer 0 (din=80) -----
    gemm_dual<80><<<GEMM_BLOCKS, 256, 0, stream>>>(h0, l_pW[0], l_dW[0], hlin_p, hlin_d);
    compute_sd<<<(N_NODES * 4 + GB - 1) / GB, GB, 0, stream>>>(hlin_p, hlin_d,
        l_pas[0], l_pad[0], l_das[0], l_dad[0], s_p, d_p, s_d, d_d);
    gat_agg<<<(N_NODES + 3) / 4, 256, 0, stream>>>(hlin_p, hlin_d, s_p, d_p, s_d, d_d,
        csr_off, sorted_src, l_posW[0], l_posb[0], gat_cat);
    hipMemsetAsync(stats, 0, 128 * sizeof(float), stream);
    gemm_single<128, true><<<GEMM_BLOCKS, 256, 0, stream>>>(gat_cat, l_fW[0], l_fb[0], F0, stats);
    bn_elu<<<(N_NODES * 64 + GB - 1) / GB, GB, 0, stream>>>(F0, stats, l_g[0], l_b[0], nullptr);

    // ----- layer 1 (din=64) -----
    gemm_dual<64><<<GEMM_BLOCKS, 256, 0, stream>>>(F0, l_pW[1], l_dW[1], hlin_p, hlin_d);
    compute_sd<<<(N_NODES * 4 + GB - 1) / GB, GB, 0, stream>>>(hlin_p, hlin_d,
        l_pas[1], l_pad[1], l_das[1], l_dad[1], s_p, d_p, s_d, d_d);
    gat_agg<<<(N_NODES + 3) / 4, 256, 0, stream>>>(hlin_p, hlin_d, s_p, d_p, s_d, d_d,
        csr_off, sorted_src, l_posW[1], l_posb[1], gat_cat);
    hipMemsetAsync(stats, 0, 128 * sizeof(float), stream);
    gemm_single<128, true><<<GEMM_BLOCKS, 256, 0, stream>>>(gat_cat, l_fW[1], l_fb[1], F1, stats);
    // residual: resbuf reuses hlin_p region (dead after layer-1 aggregation)
    float* resbuf = hlin_p;
    gemm_single<64, false><<<GEMM_BLOCKS, 256, 0, stream>>>(F0, res_W, res_b, resbuf, nullptr);
    bn_elu<<<(N_NODES * 64 + GB - 1) / GB, GB, 0, stream>>>(F1, stats, l_g[1], l_b[1], resbuf);

    // ----- pool + task head + diversity loss -----
    pool_task<<<N_GRAPHS, 256, 0, stream>>>(F1, task_W, task_b, out);
    div_loss<<<1, 256, 0, stream>>>(l_dW[0], l_dW[1], out + 1000);
}

// Round 2
// 905.878 us; speedup vs baseline: 1.1154x; 1.1154x over previous
//
#include <hip/hip_runtime.h>
#include <math.h>

// ---------------- static problem config ----------------
#define N_NODES   100000
#define N_GRAPHS  100
#define NPG       1000
#define N_EDGES   1600000
#define EPG       16000      // edges per graph
#define IN_DIM    64
#define POS_DIM   16
#define HID       16
#define HEADS     4
#define HD        64         // HEADS*HID
#define OUT_DIM   10
#define BN_EPS    1e-5f
#define NEG_SLOPE 0.2f

// ---------------- workspace layout (float elements) ----------------
// Region A [0..8M)      : h0 [N,80] (dies after layer-0 gemm_dual); then ewp [E,4] (6.4M) aliases it
// hlin_p  : [N,64]          6,400,000
// hlin_d  : [N,64]          6,400,000
// gat_cat : [N,128]        12,800,000
// F0 (h1) : [N,64]          6,400,000
// F1 (h2) : [N,64]          6,400,000   <- ewd [E,4] aliases this region (written after last ewd read)
// s_p,d_p,s_d,d_d : [N,4] each  400,000 x4
// stats   : 128
// csr_off : int[100001]
// sorted_src : int[1,600,000]
static const size_t OFF_H0    = 0;
static const size_t OFF_EWP   = 0;         // aliases h0 (dead by then)
static const size_t OFF_HLP   = 8000000;
static const size_t OFF_HLD   = 14400000;
static const size_t OFF_CAT   = 20800000;
static const size_t OFF_F0    = 33600000;
static const size_t OFF_F1    = 40000000;
static const size_t OFF_EWD   = 40000000;  // aliases F1 (F1 written only after last ewd read)
static const size_t OFF_SP    = 46400000;
static const size_t OFF_DP    = 46800000;
static const size_t OFF_SD    = 47200000;
static const size_t OFF_DD    = 47600000;
static const size_t OFF_STATS = 48000000;  // 128 floats (sum[64], sumsq[64])
static const size_t OFF_CSR   = 48000128;  // int region starts here
static const size_t OFF_SRT   = 48100144;  // ints

// ---------------- h0 = [x | pos @ pe_W + pe_b] ----------------
__global__ void build_h0(const float* __restrict__ x, const float* __restrict__ peW,
                         const float* __restrict__ peb, float* __restrict__ h0) {
    int idx = blockIdx.x * blockDim.x + threadIdx.x;
    if (idx >= N_NODES * 80) return;
    int n = idx / 80;
    int c = idx - n * 80;
    if (c < 64) {
        h0[idx] = x[n * 64 + c];
    } else {
        int r = n % NPG;
        float px = (float)(r >> 5) * (1.0f / 31.0f);
        float py = (float)(r & 31) * (1.0f / 31.0f);
        int cc = c - 64;
        h0[idx] = px * peW[cc] + py * peW[16 + cc] + peb[cc];
    }
}

// ---------------- per-graph counting sort of edges by dst ----------------
__global__ __launch_bounds__(1024) void sort_edges(const int* __restrict__ ei,
                                                   int* __restrict__ csr_off,
                                                   int* __restrict__ sorted_src) {
    __shared__ int hist[1024];
    __shared__ int scan[1024];
    const int g = blockIdx.x;
    const int t = threadIdx.x;
    const int* src = ei;
    const int* dst = ei + N_EDGES;
    const int e0 = g * EPG;
    const int nbase = g * NPG;

    hist[t] = 0;
    __syncthreads();
    for (int i = t; i < EPG; i += 1024) {
        int d = dst[e0 + i] - nbase;
        atomicAdd(&hist[d], 1);
    }
    __syncthreads();
    scan[t] = hist[t];
    __syncthreads();
    for (int off = 1; off < 1024; off <<= 1) {
        int v = (t >= off) ? scan[t - off] : 0;
        __syncthreads();
        scan[t] += v;
        __syncthreads();
    }
    int excl = scan[t] - hist[t];
    if (t < NPG) csr_off[nbase + t] = e0 + excl;
    if (g == 0 && t == 0) csr_off[N_NODES] = N_EDGES;
    __syncthreads();
    hist[t] = excl;   // running counters
    __syncthreads();
    for (int i = t; i < EPG; i += 1024) {
        int s = src[e0 + i];
        int d = dst[e0 + i] - nbase;
        int slot = atomicAdd(&hist[d], 1);
        sorted_src[e0 + slot] = s;
    }
}

// ---------------- dual GEMM: hlin_p = A@Wp, hlin_d = A@Wd ----------------
template <int DIN>
__global__ __launch_bounds__(256) void gemm_dual(const float* __restrict__ A,
                                                 const float* __restrict__ Wp,
                                                 const float* __restrict__ Wd,
                                                 float* __restrict__ outp,
                                                 float* __restrict__ outd) {
    __shared__ float sWp[DIN * 64];
    __shared__ float sWd[DIN * 64];
    __shared__ float sH[64 * DIN];
    const int t = threadIdx.x;
    for (int i = t; i < DIN * 64; i += 256) { sWp[i] = Wp[i]; sWd[i] = Wd[i]; }
    const int node0 = blockIdx.x * 64;
    const int limit = (N_NODES - node0) * DIN;
    for (int i = t; i < 64 * DIN; i += 256) sH[i] = (i < limit) ? A[node0 * DIN + i] : 0.0f;
    __syncthreads();

    const int c = t & 63, q = t >> 6;
    float accp[16], accd[16];
#pragma unroll
    for (int j = 0; j < 16; ++j) { accp[j] = 0.f; accd[j] = 0.f; }

    for (int k = 0; k < DIN; k += 4) {
        float wp0 = sWp[(k + 0) * 64 + c], wp1 = sWp[(k + 1) * 64 + c];
        float wp2 = sWp[(k + 2) * 64 + c], wp3 = sWp[(k + 3) * 64 + c];
        float wd0 = sWd[(k + 0) * 64 + c], wd1 = sWd[(k + 1) * 64 + c];
        float wd2 = sWd[(k + 2) * 64 + c], wd3 = sWd[(k + 3) * 64 + c];
#pragma unroll
        for (int j = 0; j < 16; ++j) {
            const float4 h4 = *reinterpret_cast<const float4*>(&sH[(q * 16 + j) * DIN + k]);
            accp[j] = fmaf(h4.w, wp3, fmaf(h4.z, wp2, fmaf(h4.y, wp1, fmaf(h4.x, wp0, accp[j]))));
            accd[j] = fmaf(h4.w, wd3, fmaf(h4.z, wd2, fmaf(h4.y, wd1, fmaf(h4.x, wd0, accd[j]))));
        }
    }
#pragma unroll
    for (int j = 0; j < 16; ++j) {
        int node = node0 + q * 16 + j;
        if (node < N_NODES) {
            outp[node * 64 + c] = accp[j];
            outd[node * 64 + c] = accd[j];
        }
    }
}

// ---------------- single GEMM (+bias, optional BN-stat accumulation) ----------------
template <int K, bool STATS>
__global__ __launch_bounds__(256) void gemm_single(const float* __restrict__ A,
                                                   const float* __restrict__ W,
                                                   const float* __restrict__ bias,
                                                   float* __restrict__ out,
                                                   float* __restrict__ stats) {
    __shared__ float sW[K * 64];
    __shared__ float sH[64 * K];
    const int t = threadIdx.x;
    for (int i = t; i < K * 64; i += 256) sW[i] = W[i];
    const int node0 = blockIdx.x * 64;
    const int limit = (N_NODES - node0) * K;
    for (int i = t; i < 64 * K; i += 256) sH[i] = (i < limit) ? A[node0 * K + i] : 0.0f;
    __syncthreads();

    const int c = t & 63, q = t >> 6;
    float acc[16];
#pragma unroll
    for (int j = 0; j < 16; ++j) acc[j] = 0.f;

    for (int k = 0; k < K; k += 4) {
        float w0 = sW[(k + 0) * 64 + c], w1 = sW[(k + 1) * 64 + c];
        float w2 = sW[(k + 2) * 64 + c], w3 = sW[(k + 3) * 64 + c];
#pragma unroll
        for (int j = 0; j < 16; ++j) {
            const float4 h4 = *reinterpret_cast<const float4*>(&sH[(q * 16 + j) * K + k]);
            acc[j] = fmaf(h4.w, w3, fmaf(h4.z, w2, fmaf(h4.y, w1, fmaf(h4.x, w0, acc[j]))));
        }
    }
    const float bc = bias[c];
    float lsum = 0.f, lsq = 0.f;
#pragma unroll
    for (int j = 0; j < 16; ++j) {
        int node = node0 + q * 16 + j;
        if (node < N_NODES) {
            float v = acc[j] + bc;
            out[node * 64 + c] = v;
            lsum += v;
            lsq += v * v;
        }
    }
    if (STATS) {
        __syncthreads();
        float* red = sH;
        red[t] = lsum;
        red[256 + t] = lsq;
        __syncthreads();
        if (t < 64) {
            float s  = red[c] + red[64 + c] + red[128 + c] + red[192 + c];
            float sq = red[256 + c] + red[320 + c] + red[384 + c] + red[448 + c];
            atomicAdd(&stats[c], s);
            atomicAdd(&stats[64 + c], sq);
        }
    }
}

// ---------------- per-(node,head) attention logits ----------------
__global__ void compute_sd(const float* __restrict__ hp, const float* __restrict__ hd,
                           const float* __restrict__ pas, const float* __restrict__ pad_,
                           const float* __restrict__ das, const float* __restrict__ dad,
                           float* __restrict__ sp, float* __restrict__ dp,
                           float* __restrict__ sd, float* __restrict__ dd) {
    int idx = blockIdx.x * blockDim.x + threadIdx.x;
    if (idx >= N_NODES * 4) return;
    int n = idx >> 2, h = idx & 3;
    const float* rowp = hp + n * 64 + h * 16;
    const float* rowd = hd + n * 64 + h * 16;
    float ap = 0.f, bp = 0.f, ad = 0.f, bd = 0.f;
#pragma unroll
    for (int i = 0; i < 16; ++i) {
        float vp = rowp[i], vd = rowd[i];
        ap += vp * pas[h * 16 + i];
        bp += vp * pad_[h * 16 + i];
        ad += vd * das[h * 16 + i];
        bd += vd * dad[h * 16 + i];
    }
    sp[idx] = ap; dp[idx] = bp; sd[idx] = ad; dd[idx] = bd;
}

// ---------------- per-(edge,head) softmax weights (computed ONCE, not per lane) ----------------
__global__ __launch_bounds__(256) void edge_weights(const float* __restrict__ s_p,
                                                    const float* __restrict__ d_p,
                                                    const float* __restrict__ s_d,
                                                    const float* __restrict__ d_d,
                                                    const int* __restrict__ csr_off,
                                                    const int* __restrict__ sorted_src,
                                                    const float* __restrict__ posW,
                                                    const float* __restrict__ posb,
                                                    float* __restrict__ ewp,
                                                    float* __restrict__ ewd) {
    int v = blockIdx.x * 4 + (threadIdx.x >> 6);
    if (v >= N_NODES) return;
    const int lane = threadIdx.x & 63;
    const int h = lane & 3;        // head
    const int j = lane >> 2;       // edge slot 0..15

    int r = v % NPG;
    const float px = (float)(r >> 5) * (1.0f / 31.0f);
    const float py = (float)(r & 31) * (1.0f / 31.0f);
    const float pw0 = posW[h], pw1 = posW[4 + h], pb = posb[h];
    const float dpv = d_p[v * 4 + h];
    const float ddv = d_d[v * 4 + h];

    const int beg = csr_off[v];
    const int end = csr_off[v + 1];
    for (int e = beg + j; e < end; e += 16) {
        int src = sorted_src[e];
        int rs = src % NPG;
        float sx = (float)(rs >> 5) * (1.0f / 31.0f);
        float sy = (float)(rs & 31) * (1.0f / 31.0f);
        float extra = (px - sx) * pw0 + (py - sy) * pw1 + pb;
        float ep = s_p[src * 4 + h] + dpv + extra;
        float ed = s_d[src * 4 + h] + ddv;
        ep = fmaxf(ep, NEG_SLOPE * ep);     // leaky_relu (slope<1)
        ed = fmaxf(ed, NEG_SLOPE * ed);
        ewp[e * 4 + h] = __expf(ep);
        ewd[e * 4 + h] = __expf(ed);
    }
}

// ---------------- lean dual-GAT aggregation: one wave per dst node ----------------
__global__ __launch_bounds__(256) void gat_agg(const float* __restrict__ hlin_p,
                                               const float* __restrict__ hlin_d,
                                               const float* __restrict__ ewp,
                                               const float* __restrict__ ewd,
                                               const int* __restrict__ csr_off,
                                               const int* __restrict__ sorted_src,
                                               float* __restrict__ gat_cat) {
    // XCD-aware swizzle: grid = 25000 = 8 * 3125; keep each graph's blocks on one XCD
    const int b = blockIdx.x;
    const int logical = (b & 7) * 3125 + (b >> 3);
    const int v = logical * 4 + (threadIdx.x >> 6);
    if (v >= N_NODES) return;
    const int lane = threadIdx.x & 63;
    const int head = lane >> 4;

    const float* hp = hlin_p + lane;
    const float* hd = hlin_d + lane;

    const int beg = csr_off[v];
    const int end = csr_off[v + 1];
    float accp = 0.f, accd = 0.f, denp = 0.f, dend = 0.f;
#pragma unroll 2
    for (int e = beg; e < end; ++e) {
        int src = sorted_src[e];
        float pp = ewp[e * 4 + head];
        float pd = ewd[e * 4 + head];
        accp = fmaf(pp, hp[(size_t)src * 64], accp);
        accd = fmaf(pd, hd[(size_t)src * 64], accd);
        denp += pp;
        dend += pd;
    }
    gat_cat[v * 128 + lane]      = accp / (denp + 1e-16f);
    gat_cat[v * 128 + 64 + lane] = accd / (dend + 1e-16f);
}

// ---------------- BN (from accumulated stats) + ELU (+ optional residual add) ----------------
__global__ void bn_elu(float* __restrict__ F, const float* __restrict__ stats,
                       const float* __restrict__ gamma, const float* __restrict__ beta,
                       const float* __restrict__ res) {
    int idx = blockIdx.x * blockDim.x + threadIdx.x;
    if (idx >= N_NODES * 64) return;
    int c = idx & 63;
    float mu = stats[c] * (1.0f / (float)N_NODES);
    float var = stats[64 + c] * (1.0f / (float)N_NODES) - mu * mu;
    float inv = rsqrtf(var + BN_EPS);
    float v = (F[idx] - mu) * inv * gamma[c] + beta[c];
    v = (v > 0.f) ? v : expm1f(v);
    if (res) v += res[idx];
    F[idx] = v;
}

// ---------------- mean pool per graph + task head ----------------
__global__ __launch_bounds__(256) void pool_task(const float* __restrict__ h2,
                                                 const float* __restrict__ taskW,
                                                 const float* __restrict__ taskb,
                                                 float* __restrict__ out) {
    __shared__ float red[256];
    __shared__ float pooled[64];
    const int g = blockIdx.x;
    const int t = threadIdx.x;
    const int c = t & 63, q = t >> 6;
    float acc = 0.f;
    for (int nl = q; nl < NPG; nl += 4) acc += h2[(g * NPG + nl) * 64 + c];
    red[t] = acc;
    __syncthreads();
    if (t < 64) pooled[c] = (red[c] + red[64 + c] + red[128 + c] + red[192 + c]) * (1.0f / (float)NPG);
    __syncthreads();
    if (t < OUT_DIM) {
        float o = taskb[t];
        for (int cc = 0; cc < 64; ++cc) o += pooled[cc] * taskW[cc * OUT_DIM + t];
        out[g * OUT_DIM + t] = o;
    }
}

// ---------------- head-diversity loss for both layers ----------------
__global__ __launch_bounds__(256) void div_loss(const float* __restrict__ dW0,
                                                const float* __restrict__ dW1,
                                                float* __restrict__ out) {
    __shared__ float red[16][16];
    float total = 0.f;
    for (int layer = 0; layer < 2; ++layer) {
        const float* W = layer ? dW1 : dW0;
        const int din = layer ? 64 : 80;
        const int p = threadIdx.x & 15;
        const int s16 = threadIdx.x >> 4;
        const int i = p >> 2, j = p & 3;
        float acc = 0.f;
        const int Kk = din * 16;
        for (int kk = s16; kk < Kk; kk += 16) {
            int rrow = kk >> 4, cc = kk & 15;
            acc += W[rrow * 64 + i * 16 + cc] * W[rrow * 64 + j * 16 + cc];
        }
        red[p][s16] = acc;
        __syncthreads();
        if (threadIdx.x < 16) {
            float s = 0.f;
            for (int m = 0; m < 16; ++m) s += red[threadIdx.x][m];
            red[threadIdx.x][0] = s;
        }
        __syncthreads();
        if (threadIdx.x == 0) {
            float G[4][4], nrm[4];
            for (int a = 0; a < 4; ++a)
                for (int b = 0; b < 4; ++b) G[a][b] = red[a * 4 + b][0];
            for (int a = 0; a < 4; ++a) nrm[a] = sqrtf(G[a][a]) + 1e-12f;
            float l = 0.f;
            for (int a = 0; a < 4; ++a)
                for (int b = 0; b < 4; ++b) {
                    float gn = G[a][b] / (nrm[a] * nrm[b]);
                    float off = gn - (a == b ? 1.f : 0.f);
                    l += off * off;
                }
            total += 0.1f * l / 12.f;
        }
        __syncthreads();
    }
    if (threadIdx.x == 0) *out = total;
}

// ---------------- launcher ----------------
extern "C" void kernel_launch(void* const* d_in, const int* in_sizes, int n_in,
                              void* d_out, int out_size, void* d_ws, size_t ws_size,
                              hipStream_t stream) {
    const float* x      = (const float*)d_in[0];
    const int*   ei     = (const int*)d_in[1];
    const float* peW    = (const float*)d_in[3];
    const float* peb    = (const float*)d_in[4];

    const float* l_pW[2]   = {(const float*)d_in[5],  (const float*)d_in[17]};
    const float* l_pas[2]  = {(const float*)d_in[6],  (const float*)d_in[18]};
    const float* l_pad[2]  = {(const float*)d_in[7],  (const float*)d_in[19]};
    const float* l_posW[2] = {(const float*)d_in[8],  (const float*)d_in[20]};
    const float* l_posb[2] = {(const float*)d_in[9],  (const float*)d_in[21]};
    const float* l_dW[2]   = {(const float*)d_in[10], (const float*)d_in[22]};
    const float* l_das[2]  = {(const float*)d_in[11], (const float*)d_in[23]};
    const float* l_dad[2]  = {(const float*)d_in[12], (const float*)d_in[24]};
    const float* l_fW[2]   = {(const float*)d_in[13], (const float*)d_in[25]};
    const float* l_fb[2]   = {(const float*)d_in[14], (const float*)d_in[26]};
    const float* l_g[2]    = {(const float*)d_in[15], (const float*)d_in[27]};
    const float* l_b[2]    = {(const float*)d_in[16], (const float*)d_in[28]};
    const float* res_W  = (const float*)d_in[29];
    const float* res_b  = (const float*)d_in[30];
    const float* task_W = (const float*)d_in[31];
    const float* task_b = (const float*)d_in[32];

    float* ws = (float*)d_ws;
    float* h0      = ws + OFF_H0;
    float* ewp     = ws + OFF_EWP;   // aliases h0
    float* hlin_p  = ws + OFF_HLP;
    float* hlin_d  = ws + OFF_HLD;
    float* gat_cat = ws + OFF_CAT;
    float* F0      = ws + OFF_F0;
    float* F1      = ws + OFF_F1;
    float* ewd     = ws + OFF_EWD;   // aliases F1
    float* s_p     = ws + OFF_SP;
    float* d_p     = ws + OFF_DP;
    float* s_d     = ws + OFF_SD;
    float* d_d     = ws + OFF_DD;
    float* stats   = ws + OFF_STATS;
    int*   csr_off    = (int*)(ws + OFF_CSR);
    int*   sorted_src = (int*)(ws + OFF_SRT);
    float* out = (float*)d_out;

    const int GB = 256;
    const int NODE_BLOCKS = (N_NODES + 3) / 4;      // 25000
    const int GEMM_BLOCKS = (N_NODES + 63) / 64;    // 1563

    build_h0<<<(N_NODES * 80 + GB - 1) / GB, GB, 0, stream>>>(x, peW, peb, h0);
    sort_edges<<<N_GRAPHS, 1024, 0, stream>>>(ei, csr_off, sorted_src);

    // ----- layer 0 (din=80) -----
    gemm_dual<80><<<GEMM_BLOCKS, 256, 0, stream>>>(h0, l_pW[0], l_dW[0], hlin_p, hlin_d);
    compute_sd<<<(N_NODES * 4 + GB - 1) / GB, GB, 0, stream>>>(hlin_p, hlin_d,
        l_pas[0], l_pad[0], l_das[0], l_dad[0], s_p, d_p, s_d, d_d);
    edge_weights<<<NODE_BLOCKS, 256, 0, stream>>>(s_p, d_p, s_d, d_d,
        csr_off, sorted_src, l_posW[0], l_posb[0], ewp, ewd);
    gat_agg<<<NODE_BLOCKS, 256, 0, stream>>>(hlin_p, hlin_d, ewp, ewd,
        csr_off, sorted_src, gat_cat);
    hipMemsetAsync(stats, 0, 128 * sizeof(float), stream);
    gemm_single<128, true><<<GEMM_BLOCKS, 256, 0, stream>>>(gat_cat, l_fW[0], l_fb[0], F0, stats);
    bn_elu<<<(N_NODES * 64 + GB - 1) / GB, GB, 0, stream>>>(F0, stats, l_g[0], l_b[0], nullptr);

    // ----- layer 1 (din=64) -----
    gemm_dual<64><<<GEMM_BLOCKS, 256, 0, stream>>>(F0, l_pW[1], l_dW[1], hlin_p, hlin_d);
    compute_sd<<<(N_NODES * 4 + GB - 1) / GB, GB, 0, stream>>>(hlin_p, hlin_d,
        l_pas[1], l_pad[1], l_das[1], l_dad[1], s_p, d_p, s_d, d_d);
    edge_weights<<<NODE_BLOCKS, 256, 0, stream>>>(s_p, d_p, s_d, d_d,
        csr_off, sorted_src, l_posW[1], l_posb[1], ewp, ewd);
    gat_agg<<<NODE_BLOCKS, 256, 0, stream>>>(hlin_p, hlin_d, ewp, ewd,
        csr_off, sorted_src, gat_cat);
    hipMemsetAsync(stats, 0, 128 * sizeof(float), stream);
    gemm_single<128, true><<<GEMM_BLOCKS, 256, 0, stream>>>(gat_cat, l_fW[1], l_fb[1], F1, stats);
    float* resbuf = hlin_p;
    gemm_single<64, false><<<GEMM_BLOCKS, 256, 0, stream>>>(F0, res_W, res_b, resbuf, nullptr);
    bn_elu<<<(N_NODES * 64 + GB - 1) / GB, GB, 0, stream>>>(F1, stats, l_g[1], l_b[1], resbuf);

    // ----- pool + task head + diversity loss -----
    pool_task<<<N_GRAPHS, 256, 0, stream>>>(F1, task_W, task_b, out);
    div_loss<<<1, 256, 0, stream>>>(l_dW[0], l_dW[1], out + 1000);
}